// Round 6
// baseline (147.012 us; speedup 1.0000x reference)
//
#include <hip/hip_runtime.h>
#include <math.h>

// N=100000 nodes, E=6400000 edges, avg degree 64.
// out[n] = [cos(th_n), sin(th_n), w_n],  w_n = S_y / max(||S||, eps),
//   S_x = cos(th)*C + sin(th)*S,  S_y = cos(th)*S - sin(th)*C,
//   C_n = sum_{e:dst=n} cos(x[src_e]),  S_n = sum_{e:dst=n} sin(x[src_e]).
//
// Model (R1-R20): rescan latency-bound at 0.57 cyc/visit (R1-R15); bin+
// accum visits each edge once (R16-R17, 175.8->139.2). R18 REGRESSION:
// cross-block SAME-LINE cursor atomics -- never again. R19/R20 flat:
// barriers and MLP depth are NOT the cost; serialization is:
//   bin  ~2.9 cyc/edge  = 16-counter LDS same-address RMW (4-way/instr)
//   accum+reduce: 51.2MB partials written then re-read + extra dispatch
// R21: (a) lane-group-sharded stage counters: idx = p*4+(lane>>4), 64
// counters -> ~1 lane/counter/instr; stage [16][4][144] = 36.9KB (still
// 4 blk/CU). (b) accum flushes lacc via DIFFERENT-address global u64
// atomicAdd into acc[N] (each addr hit exactly 32x, spread in time; not
// the R18 pattern); reduce (51.2MB) -> final (0.8MB). u64 add is
// commutative+associative => bit-identical output.
// Fixed-point u64: addend=(1<<52)|(sin+32768)<<26|(cos+32768), scale
// 2^15; per-node TOTAL degree (~64, max ~110) << 1023 => 26-bit fields
// never carry even for the full (unsliced) per-node sum.

#define EPS 1e-12f
#define NPART 16
#define RNODES 6250      // nodes per partition; u64[6250] = 50KB LDS
#define RMAX 6250
#define BLK 1024

// ---- binning ----
#define NBIN 1024        // bin blocks; chunk = ceil8(E/NBIN) = 6256 edges
#define BINBLK 512
#define CAP 512          // records per (bin-block, partition) cell;
                         // mean 391, sigma ~19 => +6.3 sigma slack
#define NSUB 4           // stage counter shards per partition (lane>>4)
#define SUBCAP 144       // per (partition,sub) stage cap; mean 97.8+-9.6
                         // => +4.8 sigma; overflow -> exact insurance
#define OCAP 262144      // overflow insurance (expected ~0 used)

static __device__ __forceinline__ unsigned long long pack_cs(float xv) {
    float sn, cs;
    __sincosf(xv, &sn, &cs);
    const int ci = __float2int_rn(cs * 32768.0f);   // [-32768, 32768]
    const int si = __float2int_rn(sn * 32768.0f);
    return (1ull << 52)
         | ((unsigned long long)(unsigned)(si + 32768) << 26)
         | (unsigned long long)(unsigned)(ci + 32768);
}

// ---------------- prep (fallback paths only) ----------------
__global__ __launch_bounds__(256) void prep_pack_kernel(
        const float* __restrict__ x,
        unsigned long long* __restrict__ pu, int N) {
    int i = blockIdx.x * blockDim.x + threadIdx.x;
    if (i < N) pu[i] = pack_cs(x[i]);
}

// ---------------- R21 bin: lane-group-sharded counters ------------------
__global__ __launch_bounds__(BINBLK, 8) void bin_kernel(
        const float* __restrict__ x,
        const int* __restrict__ esrc,
        const int* __restrict__ edst,
        unsigned long long* __restrict__ pu,   // [N+1], pu[N]=0
        unsigned* __restrict__ records,        // [NBIN][NPART][CAP]
        int* __restrict__ counts,              // [NBIN][NPART]
        unsigned long long* __restrict__ oflow,
        int* __restrict__ oflow_cnt,
        int E, int N) {
    __shared__ unsigned stage[NPART * NSUB * SUBCAP];   // 36.9KB
    __shared__ int scur[NPART * NSUB];                  // 64 counters

    // folded prep: this block's slice of the packed-addend table
    {
        const int PPB = (N + NBIN) / NBIN;     // covers [0, N] across NBIN
        const int idx = blockIdx.x * PPB + threadIdx.x;
        if (threadIdx.x < PPB && idx <= N)
            pu[idx] = (idx < N) ? pack_cs(x[idx]) : 0ull;
    }
    if (threadIdx.x < NPART * NSUB) scur[threadIdx.x] = 0;
    __syncthreads();

    const int chunk = (((E + NBIN - 1) / NBIN) + 7) & ~7;   // 8-aligned
    const int beg = blockIdx.x * chunk;
    const int end = min(beg + chunk, E);
    const int end8 = beg + (max(end - beg, 0) & ~7);
    unsigned* __restrict__ myrec =
        records + (size_t)blockIdx.x * (NPART * CAP);
    const int wave = threadIdx.x >> 6;
    const int lane = threadIdx.x & 63;
    const int sub = (threadIdx.x >> 4) & (NSUB - 1);   // lane>>4

#define BIN_ONE(dd, ss) do {                                              \
        const unsigned d_ = (unsigned)(dd);                               \
        const unsigned p_ = d_ / RNODES;        /* magic-mul const div */ \
        const unsigned dl_ = d_ - p_ * RNODES;  /* < 6250 < 2^13 */       \
        const unsigned rec_ = ((unsigned)(ss) << 13) | dl_;               \
        const unsigned ci_ = p_ * NSUB + sub;   /* ~1 lane/ctr/instr */   \
        const int slot_ = atomicAdd(&scur[ci_], 1);                       \
        if (slot_ < SUBCAP) {                                             \
            stage[ci_ * SUBCAP + slot_] = rec_;                           \
        } else {                                 /* insurance only */     \
            const int g_ = atomicAdd(oflow_cnt, 1);                       \
            if (g_ < OCAP)                                                \
                oflow[g_] = ((unsigned long long)(unsigned)(ss) << 32)    \
                          | d_;                                           \
        }                                                                 \
    } while (0)

    // stage the ENTIRE chunk: 8 edges/thread in flight, no mid barriers
    for (int i = beg + threadIdx.x * 8; i < end8; i += BINBLK * 8) {
        const int4 da = *(const int4*)&edst[i];
        const int4 db = *(const int4*)&edst[i + 4];
        const int4 sa = *(const int4*)&esrc[i];
        const int4 sb = *(const int4*)&esrc[i + 4];
        BIN_ONE(da.x, sa.x);
        BIN_ONE(da.y, sa.y);
        BIN_ONE(da.z, sa.z);
        BIN_ONE(da.w, sa.w);
        BIN_ONE(db.x, sb.x);
        BIN_ONE(db.y, sb.y);
        BIN_ONE(db.z, sb.z);
        BIN_ONE(db.w, sb.w);
    }
    for (int i = end8 + threadIdx.x; i < end; i += BINBLK)
        BIN_ONE(edst[i], esrc[i]);
#undef BIN_ONE

    __syncthreads();
    // single flush: wave w exclusively owns partitions 2w, 2w+1;
    // concatenate the 4 sub-runs into the cell, pad to x8.
    #pragma unroll
    for (int q = 0; q < 2; ++q) {
        const int p = wave * 2 + q;
        int bc[NSUB], off[NSUB];
        int total = 0;
        #pragma unroll
        for (int s4 = 0; s4 < NSUB; ++s4) {
            bc[s4] = min(scur[p * NSUB + s4], (int)SUBCAP);
            off[s4] = total;
            total += bc[s4];
        }
        #pragma unroll
        for (int s4 = 0; s4 < NSUB; ++s4) {
            const unsigned* __restrict__ src =
                stage + (p * NSUB + s4) * SUBCAP;
            for (int k = lane; k < bc[s4]; k += 64) {
                const int pos = off[s4] + k;
                const unsigned rec = src[k];
                if (pos < CAP) {
                    myrec[p * CAP + pos] = rec;
                } else {                         // insurance only
                    const int g = atomicAdd(oflow_cnt, 1);
                    if (g < OCAP)
                        oflow[g] = ((unsigned long long)(rec >> 13) << 32)
                                 | (unsigned)(p * RNODES + (rec & 8191u));
                }
            }
        }
        const int wr = min(total, (int)CAP);
        const int c8 = min((wr + 7) & ~7, (int)CAP);
        for (int k = wr + lane; k < c8; k += 64)
            myrec[p * CAP + k] = ((unsigned)N << 13);   // pu[N]=0 pad
        if (lane == 0) counts[blockIdx.x * NPART + p] = c8;
    }
}

// ---------------- R21 accum: 2-cell pipeline + atomic flush -------------
__global__ __launch_bounds__(BLK, 2) void accum_kernel(
        const unsigned long long* __restrict__ pu,
        const unsigned* __restrict__ records,
        const int* __restrict__ counts,
        const unsigned long long* __restrict__ oflow,
        const int* __restrict__ oflow_cnt,
        unsigned long long* __restrict__ acc,   // [N] zeroed
        int nslice) {
    __shared__ unsigned long long lacc[RMAX];
    const int p = blockIdx.x / nslice;
    const int s = blockIdx.x % nslice;   // XCD = s%8, matches bin b%8

    for (int k = threadIdx.x; k < RNODES; k += BLK) lacc[k] = 0ull;
    __syncthreads();

    const int wave = threadIdx.x >> 6;
    const int lane = threadIdx.x & 63;
    const int wstep = (BLK / 64) * nslice;     // 512; NBIN/wstep = 2 cells

    // ---- issue phase: both cells' cnts + record loads up front ----
    const int c0 = s + wave * nslice;
    const int c1 = c0 + wstep;
    const int cnt0 = (c0 < NBIN) ? counts[c0 * NPART + p] : 0;
    const int cnt1 = (c1 < NBIN) ? counts[c1 * NPART + p] : 0;
    const unsigned* __restrict__ b0 =
        records + ((size_t)(c0 * NPART + p)) * CAP + lane * 8;
    const unsigned* __restrict__ b1 =
        records + ((size_t)(c1 * NPART + p)) * CAP + lane * 8;
    // CAP = 512 = 64 lanes x 8 => each cell is exactly one round
    const bool a0 = lane * 8 < cnt0;
    const bool a1 = lane * 8 < cnt1;
    uint4 ra0 = make_uint4(0, 0, 0, 0), rb0 = make_uint4(0, 0, 0, 0);
    uint4 ra1 = make_uint4(0, 0, 0, 0), rb1 = make_uint4(0, 0, 0, 0);
    if (a0) { ra0 = *(const uint4*)b0; rb0 = *(const uint4*)(b0 + 4); }
    if (a1) { ra1 = *(const uint4*)b1; rb1 = *(const uint4*)(b1 + 4); }

    // ---- cell 0: 8 gathers in flight, then 8 LDS atomics ----
    if (a0) {
        const unsigned long long v0 = pu[ra0.x >> 13];
        const unsigned long long v1 = pu[ra0.y >> 13];
        const unsigned long long v2 = pu[ra0.z >> 13];
        const unsigned long long v3 = pu[ra0.w >> 13];
        const unsigned long long v4 = pu[rb0.x >> 13];
        const unsigned long long v5 = pu[rb0.y >> 13];
        const unsigned long long v6 = pu[rb0.z >> 13];
        const unsigned long long v7 = pu[rb0.w >> 13];
        atomicAdd(&lacc[ra0.x & 8191], v0);
        atomicAdd(&lacc[ra0.y & 8191], v1);
        atomicAdd(&lacc[ra0.z & 8191], v2);
        atomicAdd(&lacc[ra0.w & 8191], v3);
        atomicAdd(&lacc[rb0.x & 8191], v4);
        atomicAdd(&lacc[rb0.y & 8191], v5);
        atomicAdd(&lacc[rb0.z & 8191], v6);
        atomicAdd(&lacc[rb0.w & 8191], v7);
    }
    // ---- cell 1 ----
    if (a1) {
        const unsigned long long v0 = pu[ra1.x >> 13];
        const unsigned long long v1 = pu[ra1.y >> 13];
        const unsigned long long v2 = pu[ra1.z >> 13];
        const unsigned long long v3 = pu[ra1.w >> 13];
        const unsigned long long v4 = pu[rb1.x >> 13];
        const unsigned long long v5 = pu[rb1.y >> 13];
        const unsigned long long v6 = pu[rb1.z >> 13];
        const unsigned long long v7 = pu[rb1.w >> 13];
        atomicAdd(&lacc[ra1.x & 8191], v0);
        atomicAdd(&lacc[ra1.y & 8191], v1);
        atomicAdd(&lacc[ra1.z & 8191], v2);
        atomicAdd(&lacc[ra1.w & 8191], v3);
        atomicAdd(&lacc[rb1.x & 8191], v4);
        atomicAdd(&lacc[rb1.y & 8191], v5);
        atomicAdd(&lacc[rb1.z & 8191], v6);
        atomicAdd(&lacc[rb1.w & 8191], v7);
    }

    if (s == 0) {   // overflow insurance; expected count ~0
        const int oc = min(*oflow_cnt, (int)OCAP);
        const unsigned pBeg = (unsigned)(p * RNODES);
        for (int i = threadIdx.x; i < oc; i += BLK) {
            const unsigned long long e = oflow[i];
            const unsigned dl = (unsigned)e - pBeg;
            if (dl < (unsigned)RNODES) atomicAdd(&lacc[dl], pu[e >> 32]);
        }
    }

    __syncthreads();
    // atomic flush: different-address global u64 adds (each node hit
    // exactly nslice times, spread in time) -- NOT the R18 pattern.
    unsigned long long* __restrict__ accp = acc + (size_t)p * RNODES;
    for (int k = threadIdx.x; k < RNODES; k += BLK) {
        const unsigned long long v = lacc[k];
        if (v) atomicAdd(&accp[k], v);
    }
}

// ---------------- R21 final: unpack acc + epilogue ----------------------
__global__ __launch_bounds__(256) void final_kernel(
        const float* __restrict__ theta,
        const unsigned long long* __restrict__ acc,
        float* __restrict__ out, int N) {
    const int n = blockIdx.x * blockDim.x + threadIdx.x;
    if (n >= N) return;
    const unsigned long long t = acc[n];
    const long long k  = (long long)(t >> 52);
    const long long cf = (long long)(t & 0x3FFFFFFull);
    const long long sf = (long long)((t >> 26) & 0x3FFFFFFull);
    const float C  = (float)(cf - k * 32768) * (1.0f / 32768.0f);
    const float Sv = (float)(sf - k * 32768) * (1.0f / 32768.0f);
    float sn, cs;
    __sincosf(theta[n], &sn, &cs);
    const float nrm = fmaxf(sqrtf(C * C + Sv * Sv), EPS);
    out[3 * n + 0] = cs;
    out[3 * n + 1] = sn;
    out[3 * n + 2] = (cs * Sv - sn * C) / nrm;
}

// ---------------- R15 scatter (ws fallback): partition rescan ------------
__global__ __launch_bounds__(BLK, 2) void scatter_kernel(
        const unsigned long long* __restrict__ pu,
        const int* __restrict__ esrc,
        const int* __restrict__ edst,
        unsigned long long* __restrict__ partials,
        int E, int R, int nslice) {
    __shared__ unsigned long long lacc[RMAX];
    const int p = blockIdx.x / nslice;
    const int s = blockIdx.x % nslice;
    const int pBeg = p * R;

    for (int k = threadIdx.x; k < R; k += BLK) lacc[k] = 0ull;
    __syncthreads();

    const int per = (((E + nslice - 1) / nslice) + 7) & ~7;
    const int beg = s * per;
    const int end = min(beg + per, E);
    const int end8 = beg + (max(end - beg, 0) & ~7);

    for (int i = beg + threadIdx.x * 8; i < end8; i += BLK * 8) {
        const int4 da = *(const int4*)&edst[i];
        const int4 db = *(const int4*)&edst[i + 4];
        const int4 sa = *(const int4*)&esrc[i];
        const int4 sb = *(const int4*)&esrc[i + 4];
        const unsigned dl0 = (unsigned)(da.x - pBeg);
        const unsigned dl1 = (unsigned)(da.y - pBeg);
        const unsigned dl2 = (unsigned)(da.z - pBeg);
        const unsigned dl3 = (unsigned)(da.w - pBeg);
        const unsigned dl4 = (unsigned)(db.x - pBeg);
        const unsigned dl5 = (unsigned)(db.y - pBeg);
        const unsigned dl6 = (unsigned)(db.z - pBeg);
        const unsigned dl7 = (unsigned)(db.w - pBeg);
        const bool h0 = dl0 < (unsigned)R, h1 = dl1 < (unsigned)R;
        const bool h2 = dl2 < (unsigned)R, h3 = dl3 < (unsigned)R;
        const bool h4 = dl4 < (unsigned)R, h5 = dl5 < (unsigned)R;
        const bool h6 = dl6 < (unsigned)R, h7 = dl7 < (unsigned)R;
        unsigned long long v0 = 0, v1 = 0, v2 = 0, v3 = 0;
        unsigned long long v4 = 0, v5 = 0, v6 = 0, v7 = 0;
        if (h0) v0 = pu[sa.x];
        if (h1) v1 = pu[sa.y];
        if (h2) v2 = pu[sa.z];
        if (h3) v3 = pu[sa.w];
        if (h4) v4 = pu[sb.x];
        if (h5) v5 = pu[sb.y];
        if (h6) v6 = pu[sb.z];
        if (h7) v7 = pu[sb.w];
        if (h0) atomicAdd(&lacc[dl0], v0);
        if (h1) atomicAdd(&lacc[dl1], v1);
        if (h2) atomicAdd(&lacc[dl2], v2);
        if (h3) atomicAdd(&lacc[dl3], v3);
        if (h4) atomicAdd(&lacc[dl4], v4);
        if (h5) atomicAdd(&lacc[dl5], v5);
        if (h6) atomicAdd(&lacc[dl6], v6);
        if (h7) atomicAdd(&lacc[dl7], v7);
    }
    for (int i = end8 + threadIdx.x; i < end; i += BLK) {
        const unsigned dl = (unsigned)(edst[i] - pBeg);
        if (dl < (unsigned)R) atomicAdd(&lacc[dl], pu[esrc[i]]);
    }

    __syncthreads();
    unsigned long long* dst = partials + (size_t)blockIdx.x * R;
    for (int k = threadIdx.x; k < R; k += BLK) dst[k] = lacc[k];
}

// ---------------- reduce partials (fallback path) ----------------------
__global__ __launch_bounds__(256) void reduce_kernel(
        const float* __restrict__ theta,
        const unsigned long long* __restrict__ partials,
        float* __restrict__ out, int N, int R, int nslice) {
    const int n = blockIdx.x * blockDim.x + threadIdx.x;
    if (n >= N) return;
    const int p = n / R;
    const int j = n - p * R;
    const unsigned long long* base = partials + (size_t)p * nslice * R + j;
    unsigned long long t = 0ull;
    #pragma unroll 16
    for (int s = 0; s < nslice; ++s) t += base[(size_t)s * R];
    const long long k  = (long long)(t >> 52);
    const long long cf = (long long)(t & 0x3FFFFFFull);
    const long long sf = (long long)((t >> 26) & 0x3FFFFFFull);
    const float C  = (float)(cf - k * 32768) * (1.0f / 32768.0f);
    const float Sv = (float)(sf - k * 32768) * (1.0f / 32768.0f);
    float sn, cs;
    __sincosf(theta[n], &sn, &cs);
    const float nrm = fmaxf(sqrtf(C * C + Sv * Sv), EPS);
    out[3 * n + 0] = cs;
    out[3 * n + 1] = sn;
    out[3 * n + 2] = (cs * Sv - sn * C) / nrm;
}

// ---------------- R8 fallback: global native atomics ----------------
__global__ __launch_bounds__(256) void prep_acc_kernel(float2* __restrict__ acc, int N) {
    int i = blockIdx.x * blockDim.x + threadIdx.x;
    if (i < N) acc[i] = make_float2(0.0f, 0.0f);
}

__global__ __launch_bounds__(256) void edge_scatter_sincos_kernel(
        const int* __restrict__ esrc,
        const int* __restrict__ edst,
        const float* __restrict__ x,
        float2* __restrict__ acc, int E) {
    const int i = (blockIdx.x * 256 + threadIdx.x) * 4;
    float* accf = (float*)acc;
    for (int k = i; k < min(i + 4, E); ++k) {
        float sn, cs;
        __sincosf(x[esrc[k]], &sn, &cs);
        const int d = edst[k];
        unsafeAtomicAdd(&accf[2 * d],     cs);
        unsafeAtomicAdd(&accf[2 * d + 1], sn);
    }
}

__global__ __launch_bounds__(256) void node_kernel(
        const float* __restrict__ theta,
        const float2* __restrict__ acc,
        float* __restrict__ out, int N) {
    int n = blockIdx.x * blockDim.x + threadIdx.x;
    if (n >= N) return;
    float sn, cs;
    __sincosf(theta[n], &sn, &cs);
    const float2 a = acc[n];
    const float nrm = fmaxf(sqrtf(a.x * a.x + a.y * a.y), EPS);
    out[3 * n + 0] = cs;
    out[3 * n + 1] = sn;
    out[3 * n + 2] = (cs * a.y - sn * a.x) / nrm;
}

extern "C" void kernel_launch(void* const* d_in, const int* in_sizes, int n_in,
                              void* d_out, int out_size, void* d_ws, size_t ws_size,
                              hipStream_t stream) {
    const float* x     = (const float*)d_in[0];
    const float* theta = (const float*)d_in[1];
    const int*   esrc  = (const int*)d_in[2];
    const int*   edst  = (const int*)d_in[3];
    float*       out   = (float*)d_out;

    const int N = in_sizes[0];
    const int E = in_sizes[2];

    // ---------- R21 main path: sharded bin -> accum -> atomic acc -------
    if (N <= NPART * RNODES && N < (1 << 19)
        && (size_t)(N + 1) <= (size_t)NBIN * BINBLK) {
        const int nslice = 32;                       // accum grid 512 = 2/CU
        const size_t acc_bytes  = (size_t)NPART * RNODES * 8ull;  // 800KB
        const size_t ofc_bytes  = 64;
        const size_t pu_bytes   = (((size_t)(N + 1) * 8ull) + 15) & ~(size_t)15;
        const size_t rec_bytes  = (size_t)NBIN * NPART * CAP * 4ull;
        const size_t cnt_bytes  = (size_t)NBIN * NPART * 4ull;
        const size_t ofl_bytes  = (size_t)OCAP * 8ull;
        const size_t total = acc_bytes + ofc_bytes + pu_bytes + rec_bytes
                           + cnt_bytes + ofl_bytes;
        if (ws_size >= total) {
            char* w = (char*)d_ws;
            unsigned long long* acc      = (unsigned long long*)w; w += acc_bytes;
            int*                oflow_cnt= (int*)w;                w += ofc_bytes;
            unsigned long long* pu       = (unsigned long long*)w; w += pu_bytes;
            unsigned*           records  = (unsigned*)w;           w += rec_bytes;
            int*                counts   = (int*)w;                w += cnt_bytes;
            unsigned long long* oflow    = (unsigned long long*)w;

            // one memset covers acc (contiguous) + overflow counter
            hipMemsetAsync(acc, 0, acc_bytes + ofc_bytes, stream);
            bin_kernel<<<NBIN, BINBLK, 0, stream>>>(
                x, esrc, edst, pu, records, counts, oflow, oflow_cnt, E, N);
            accum_kernel<<<NPART * nslice, BLK, 0, stream>>>(
                pu, records, counts, oflow, oflow_cnt, acc, nslice);
            final_kernel<<<(N + 255) / 256, 256, 0, stream>>>(
                theta, acc, out, N);
            return;
        }
    }

    // ---------- R15 fallback: NPART=16 rescan, 32 waves/CU ----------
    {
        const int R = (N + NPART - 1) / NPART;
        const size_t pu_bytes = (size_t)N * sizeof(unsigned long long);
        if (R <= RMAX) {
            for (int nslice : {32, 16, 8}) {
                const size_t part_bytes =
                    (size_t)NPART * nslice * R * sizeof(unsigned long long);
                if (ws_size >= part_bytes + pu_bytes) {
                    unsigned long long* partials = (unsigned long long*)d_ws;
                    unsigned long long* pu =
                        (unsigned long long*)((char*)d_ws + part_bytes);
                    prep_pack_kernel<<<(N + 255) / 256, 256, 0, stream>>>(
                        x, pu, N);
                    scatter_kernel<<<NPART * nslice, BLK, 0, stream>>>(
                        pu, esrc, edst, partials, E, R, nslice);
                    reduce_kernel<<<(N + 255) / 256, 256, 0, stream>>>(
                        theta, partials, out, N, R, nslice);
                    return;
                }
            }
        }
    }

    // ---------- R8 fallback: global native atomics ----------
    float2* acc = (float2*)d_ws;   // 800KB
    prep_acc_kernel<<<(N + 255) / 256, 256, 0, stream>>>(acc, N);
    edge_scatter_sincos_kernel<<<(E + 1023) / 1024, 256, 0, stream>>>(esrc, edst, x, acc, E);
    node_kernel<<<(N + 255) / 256, 256, 0, stream>>>(theta, acc, out, N);
}

// Round 7
// 137.078 us; speedup vs baseline: 1.0725x; 1.0725x over previous
//
#include <hip/hip_runtime.h>
#include <math.h>

// N=100000 nodes, E=6400000 edges, avg degree 64.
// out[n] = [cos(th_n), sin(th_n), w_n],  w_n = S_y / max(||S||, eps),
//   S_x = cos(th)*C + sin(th)*S,  S_y = cos(th)*S - sin(th)*C,
//   C_n = sum_{e:dst=n} cos(x[src_e]),  S_n = sum_{e:dst=n} sin(x[src_e]).
//
// Model (R1-R21): rescan latency-bound (R1-R15). R16/R17 bin+accum
// cellular records 175.8->139.2. R18 REGRESSION (204.9): cross-block
// same-line cursor atomics. R19/R20 flat: barriers/MLP not the cost.
// R21 split result (147.0): (a) lane-group-sharded stage counters HELPED
// bin ~9-10us (16->64 LDS counters kills 4-way same-addr RMW serial);
// (b) global-atomic acc flush REGRESSED accum 28->47us (3.2M u64 atomics,
// each line RMW'd ~256x across 8 XCDs = coherence ping-pong). Lesson
// (twice now): NO cross-block same-line RMW in the hot path; streaming
// partials through L2/LLC is cheaper than "saving" the round-trip.
// R22: keep (a), revert (b) -- sharded bin + partials accum + reduce.
// Fixed-point u64: addend=(1<<52)|(sin+32768)<<26|(cos+32768), scale
// 2^15; per-node-per-slice degree << 4096 => no cross-field carry.
// u64 sums commutative+exact => bit-identical output.

#define EPS 1e-12f
#define NPART 16
#define RNODES 6250      // nodes per partition; u64[6250] = 50KB LDS
#define RMAX 6250
#define BLK 1024

// ---- binning ----
#define NBIN 1024        // bin blocks; chunk = ceil8(E/NBIN) = 6256 edges
#define BINBLK 512
#define CAP 512          // records per (bin-block, partition) cell;
                         // mean 391, sigma ~19 => +6.3 sigma slack
#define NSUB 4           // stage counter shards per partition (lane>>4)
#define SUBCAP 144       // per (partition,sub) stage cap; mean 97.8+-9.6
                         // => +4.8 sigma; overflow -> exact insurance
#define OCAP 262144      // overflow insurance (expected ~0 used)

static __device__ __forceinline__ unsigned long long pack_cs(float xv) {
    float sn, cs;
    __sincosf(xv, &sn, &cs);
    const int ci = __float2int_rn(cs * 32768.0f);   // [-32768, 32768]
    const int si = __float2int_rn(sn * 32768.0f);
    return (1ull << 52)
         | ((unsigned long long)(unsigned)(si + 32768) << 26)
         | (unsigned long long)(unsigned)(ci + 32768);
}

// ---------------- prep (fallback paths only) ----------------
__global__ __launch_bounds__(256) void prep_pack_kernel(
        const float* __restrict__ x,
        unsigned long long* __restrict__ pu, int N) {
    int i = blockIdx.x * blockDim.x + threadIdx.x;
    if (i < N) pu[i] = pack_cs(x[i]);
}

// ---------------- R22 bin: lane-group-sharded counters (from R21) -------
__global__ __launch_bounds__(BINBLK, 8) void bin_kernel(
        const float* __restrict__ x,
        const int* __restrict__ esrc,
        const int* __restrict__ edst,
        unsigned long long* __restrict__ pu,   // [N+1], pu[N]=0
        unsigned* __restrict__ records,        // [NBIN][NPART][CAP]
        int* __restrict__ counts,              // [NBIN][NPART]
        unsigned long long* __restrict__ oflow,
        int* __restrict__ oflow_cnt,
        int E, int N) {
    __shared__ unsigned stage[NPART * NSUB * SUBCAP];   // 36.9KB
    __shared__ int scur[NPART * NSUB];                  // 64 counters

    // folded prep: this block's slice of the packed-addend table
    {
        const int PPB = (N + NBIN) / NBIN;     // covers [0, N] across NBIN
        const int idx = blockIdx.x * PPB + threadIdx.x;
        if (threadIdx.x < PPB && idx <= N)
            pu[idx] = (idx < N) ? pack_cs(x[idx]) : 0ull;
    }
    if (threadIdx.x < NPART * NSUB) scur[threadIdx.x] = 0;
    __syncthreads();

    const int chunk = (((E + NBIN - 1) / NBIN) + 7) & ~7;   // 8-aligned
    const int beg = blockIdx.x * chunk;
    const int end = min(beg + chunk, E);
    const int end8 = beg + (max(end - beg, 0) & ~7);
    unsigned* __restrict__ myrec =
        records + (size_t)blockIdx.x * (NPART * CAP);
    const int wave = threadIdx.x >> 6;
    const int lane = threadIdx.x & 63;
    const int sub = (threadIdx.x >> 4) & (NSUB - 1);   // lane>>4

#define BIN_ONE(dd, ss) do {                                              \
        const unsigned d_ = (unsigned)(dd);                               \
        const unsigned p_ = d_ / RNODES;        /* magic-mul const div */ \
        const unsigned dl_ = d_ - p_ * RNODES;  /* < 6250 < 2^13 */       \
        const unsigned rec_ = ((unsigned)(ss) << 13) | dl_;               \
        const unsigned ci_ = p_ * NSUB + sub;   /* ~1 lane/ctr/instr */   \
        const int slot_ = atomicAdd(&scur[ci_], 1);                       \
        if (slot_ < SUBCAP) {                                             \
            stage[ci_ * SUBCAP + slot_] = rec_;                           \
        } else {                                 /* insurance only */     \
            const int g_ = atomicAdd(oflow_cnt, 1);                       \
            if (g_ < OCAP)                                                \
                oflow[g_] = ((unsigned long long)(unsigned)(ss) << 32)    \
                          | d_;                                           \
        }                                                                 \
    } while (0)

    // stage the ENTIRE chunk: 8 edges/thread in flight, no mid barriers
    for (int i = beg + threadIdx.x * 8; i < end8; i += BINBLK * 8) {
        const int4 da = *(const int4*)&edst[i];
        const int4 db = *(const int4*)&edst[i + 4];
        const int4 sa = *(const int4*)&esrc[i];
        const int4 sb = *(const int4*)&esrc[i + 4];
        BIN_ONE(da.x, sa.x);
        BIN_ONE(da.y, sa.y);
        BIN_ONE(da.z, sa.z);
        BIN_ONE(da.w, sa.w);
        BIN_ONE(db.x, sb.x);
        BIN_ONE(db.y, sb.y);
        BIN_ONE(db.z, sb.z);
        BIN_ONE(db.w, sb.w);
    }
    for (int i = end8 + threadIdx.x; i < end; i += BINBLK)
        BIN_ONE(edst[i], esrc[i]);
#undef BIN_ONE

    __syncthreads();
    // single flush: wave w exclusively owns partitions 2w, 2w+1;
    // concatenate the 4 sub-runs into the cell, pad to x8.
    #pragma unroll
    for (int q = 0; q < 2; ++q) {
        const int p = wave * 2 + q;
        int bc[NSUB], off[NSUB];
        int total = 0;
        #pragma unroll
        for (int s4 = 0; s4 < NSUB; ++s4) {
            bc[s4] = min(scur[p * NSUB + s4], (int)SUBCAP);
            off[s4] = total;
            total += bc[s4];
        }
        #pragma unroll
        for (int s4 = 0; s4 < NSUB; ++s4) {
            const unsigned* __restrict__ src =
                stage + (p * NSUB + s4) * SUBCAP;
            for (int k = lane; k < bc[s4]; k += 64) {
                const int pos = off[s4] + k;
                const unsigned rec = src[k];
                if (pos < CAP) {
                    myrec[p * CAP + pos] = rec;
                } else {                         // insurance only
                    const int g = atomicAdd(oflow_cnt, 1);
                    if (g < OCAP)
                        oflow[g] = ((unsigned long long)(rec >> 13) << 32)
                                 | (unsigned)(p * RNODES + (rec & 8191u));
                }
            }
        }
        const int wr = min(total, (int)CAP);
        const int c8 = min((wr + 7) & ~7, (int)CAP);
        for (int k = wr + lane; k < c8; k += 64)
            myrec[p * CAP + k] = ((unsigned)N << 13);   // pu[N]=0 pad
        if (lane == 0) counts[blockIdx.x * NPART + p] = c8;
    }
}

// ---------------- R22 accum (R20): 2-cell pipeline, partials store ------
__global__ __launch_bounds__(BLK, 2) void accum_kernel(
        const unsigned long long* __restrict__ pu,
        const unsigned* __restrict__ records,
        const int* __restrict__ counts,
        const unsigned long long* __restrict__ oflow,
        const int* __restrict__ oflow_cnt,
        unsigned long long* __restrict__ partials,   // [NPART*nslice][RNODES]
        int nslice) {
    __shared__ unsigned long long lacc[RMAX];
    const int p = blockIdx.x / nslice;
    const int s = blockIdx.x % nslice;   // XCD = s%8, matches bin b%8

    for (int k = threadIdx.x; k < RNODES; k += BLK) lacc[k] = 0ull;
    __syncthreads();

    const int wave = threadIdx.x >> 6;
    const int lane = threadIdx.x & 63;
    const int wstep = (BLK / 64) * nslice;     // 512; NBIN/wstep = 2 cells

    // ---- issue phase: both cells' cnts + record loads up front ----
    const int c0 = s + wave * nslice;
    const int c1 = c0 + wstep;
    const int cnt0 = (c0 < NBIN) ? counts[c0 * NPART + p] : 0;
    const int cnt1 = (c1 < NBIN) ? counts[c1 * NPART + p] : 0;
    const unsigned* __restrict__ b0 =
        records + ((size_t)(c0 * NPART + p)) * CAP + lane * 8;
    const unsigned* __restrict__ b1 =
        records + ((size_t)(c1 * NPART + p)) * CAP + lane * 8;
    // CAP = 512 = 64 lanes x 8 => each cell is exactly one round
    const bool a0 = lane * 8 < cnt0;
    const bool a1 = lane * 8 < cnt1;
    uint4 ra0 = make_uint4(0, 0, 0, 0), rb0 = make_uint4(0, 0, 0, 0);
    uint4 ra1 = make_uint4(0, 0, 0, 0), rb1 = make_uint4(0, 0, 0, 0);
    if (a0) { ra0 = *(const uint4*)b0; rb0 = *(const uint4*)(b0 + 4); }
    if (a1) { ra1 = *(const uint4*)b1; rb1 = *(const uint4*)(b1 + 4); }

    // ---- cell 0: 8 gathers in flight, then 8 LDS atomics ----
    if (a0) {
        const unsigned long long v0 = pu[ra0.x >> 13];
        const unsigned long long v1 = pu[ra0.y >> 13];
        const unsigned long long v2 = pu[ra0.z >> 13];
        const unsigned long long v3 = pu[ra0.w >> 13];
        const unsigned long long v4 = pu[rb0.x >> 13];
        const unsigned long long v5 = pu[rb0.y >> 13];
        const unsigned long long v6 = pu[rb0.z >> 13];
        const unsigned long long v7 = pu[rb0.w >> 13];
        atomicAdd(&lacc[ra0.x & 8191], v0);
        atomicAdd(&lacc[ra0.y & 8191], v1);
        atomicAdd(&lacc[ra0.z & 8191], v2);
        atomicAdd(&lacc[ra0.w & 8191], v3);
        atomicAdd(&lacc[rb0.x & 8191], v4);
        atomicAdd(&lacc[rb0.y & 8191], v5);
        atomicAdd(&lacc[rb0.z & 8191], v6);
        atomicAdd(&lacc[rb0.w & 8191], v7);
    }
    // ---- cell 1 ----
    if (a1) {
        const unsigned long long v0 = pu[ra1.x >> 13];
        const unsigned long long v1 = pu[ra1.y >> 13];
        const unsigned long long v2 = pu[ra1.z >> 13];
        const unsigned long long v3 = pu[ra1.w >> 13];
        const unsigned long long v4 = pu[rb1.x >> 13];
        const unsigned long long v5 = pu[rb1.y >> 13];
        const unsigned long long v6 = pu[rb1.z >> 13];
        const unsigned long long v7 = pu[rb1.w >> 13];
        atomicAdd(&lacc[ra1.x & 8191], v0);
        atomicAdd(&lacc[ra1.y & 8191], v1);
        atomicAdd(&lacc[ra1.z & 8191], v2);
        atomicAdd(&lacc[ra1.w & 8191], v3);
        atomicAdd(&lacc[rb1.x & 8191], v4);
        atomicAdd(&lacc[rb1.y & 8191], v5);
        atomicAdd(&lacc[rb1.z & 8191], v6);
        atomicAdd(&lacc[rb1.w & 8191], v7);
    }

    if (s == 0) {   // overflow insurance; expected count ~0
        const int oc = min(*oflow_cnt, (int)OCAP);
        const unsigned pBeg = (unsigned)(p * RNODES);
        for (int i = threadIdx.x; i < oc; i += BLK) {
            const unsigned long long e = oflow[i];
            const unsigned dl = (unsigned)e - pBeg;
            if (dl < (unsigned)RNODES) atomicAdd(&lacc[dl], pu[e >> 32]);
        }
    }

    __syncthreads();
    unsigned long long* dst = partials + (size_t)blockIdx.x * RNODES;
    for (int k = threadIdx.x; k < RNODES; k += BLK) dst[k] = lacc[k];
}

// ---------------- R15 scatter (ws fallback): partition rescan ------------
__global__ __launch_bounds__(BLK, 2) void scatter_kernel(
        const unsigned long long* __restrict__ pu,
        const int* __restrict__ esrc,
        const int* __restrict__ edst,
        unsigned long long* __restrict__ partials,
        int E, int R, int nslice) {
    __shared__ unsigned long long lacc[RMAX];
    const int p = blockIdx.x / nslice;
    const int s = blockIdx.x % nslice;
    const int pBeg = p * R;

    for (int k = threadIdx.x; k < R; k += BLK) lacc[k] = 0ull;
    __syncthreads();

    const int per = (((E + nslice - 1) / nslice) + 7) & ~7;
    const int beg = s * per;
    const int end = min(beg + per, E);
    const int end8 = beg + (max(end - beg, 0) & ~7);

    for (int i = beg + threadIdx.x * 8; i < end8; i += BLK * 8) {
        const int4 da = *(const int4*)&edst[i];
        const int4 db = *(const int4*)&edst[i + 4];
        const int4 sa = *(const int4*)&esrc[i];
        const int4 sb = *(const int4*)&esrc[i + 4];
        const unsigned dl0 = (unsigned)(da.x - pBeg);
        const unsigned dl1 = (unsigned)(da.y - pBeg);
        const unsigned dl2 = (unsigned)(da.z - pBeg);
        const unsigned dl3 = (unsigned)(da.w - pBeg);
        const unsigned dl4 = (unsigned)(db.x - pBeg);
        const unsigned dl5 = (unsigned)(db.y - pBeg);
        const unsigned dl6 = (unsigned)(db.z - pBeg);
        const unsigned dl7 = (unsigned)(db.w - pBeg);
        const bool h0 = dl0 < (unsigned)R, h1 = dl1 < (unsigned)R;
        const bool h2 = dl2 < (unsigned)R, h3 = dl3 < (unsigned)R;
        const bool h4 = dl4 < (unsigned)R, h5 = dl5 < (unsigned)R;
        const bool h6 = dl6 < (unsigned)R, h7 = dl7 < (unsigned)R;
        unsigned long long v0 = 0, v1 = 0, v2 = 0, v3 = 0;
        unsigned long long v4 = 0, v5 = 0, v6 = 0, v7 = 0;
        if (h0) v0 = pu[sa.x];
        if (h1) v1 = pu[sa.y];
        if (h2) v2 = pu[sa.z];
        if (h3) v3 = pu[sa.w];
        if (h4) v4 = pu[sb.x];
        if (h5) v5 = pu[sb.y];
        if (h6) v6 = pu[sb.z];
        if (h7) v7 = pu[sb.w];
        if (h0) atomicAdd(&lacc[dl0], v0);
        if (h1) atomicAdd(&lacc[dl1], v1);
        if (h2) atomicAdd(&lacc[dl2], v2);
        if (h3) atomicAdd(&lacc[dl3], v3);
        if (h4) atomicAdd(&lacc[dl4], v4);
        if (h5) atomicAdd(&lacc[dl5], v5);
        if (h6) atomicAdd(&lacc[dl6], v6);
        if (h7) atomicAdd(&lacc[dl7], v7);
    }
    for (int i = end8 + threadIdx.x; i < end; i += BLK) {
        const unsigned dl = (unsigned)(edst[i] - pBeg);
        if (dl < (unsigned)R) atomicAdd(&lacc[dl], pu[esrc[i]]);
    }

    __syncthreads();
    unsigned long long* dst = partials + (size_t)blockIdx.x * R;
    for (int k = threadIdx.x; k < R; k += BLK) dst[k] = lacc[k];
}

// ---------------- reduce partials (raw u64 sum) + epilogue ----------------
__global__ __launch_bounds__(256) void reduce_kernel(
        const float* __restrict__ theta,
        const unsigned long long* __restrict__ partials,
        float* __restrict__ out, int N, int R, int nslice) {
    const int n = blockIdx.x * blockDim.x + threadIdx.x;
    if (n >= N) return;
    const int p = n / R;
    const int j = n - p * R;
    const unsigned long long* base = partials + (size_t)p * nslice * R + j;
    unsigned long long t = 0ull;
    #pragma unroll 16
    for (int s = 0; s < nslice; ++s) t += base[(size_t)s * R];
    const long long k  = (long long)(t >> 52);
    const long long cf = (long long)(t & 0x3FFFFFFull);
    const long long sf = (long long)((t >> 26) & 0x3FFFFFFull);
    const float C  = (float)(cf - k * 32768) * (1.0f / 32768.0f);
    const float Sv = (float)(sf - k * 32768) * (1.0f / 32768.0f);
    float sn, cs;
    __sincosf(theta[n], &sn, &cs);
    const float nrm = fmaxf(sqrtf(C * C + Sv * Sv), EPS);
    out[3 * n + 0] = cs;
    out[3 * n + 1] = sn;
    out[3 * n + 2] = (cs * Sv - sn * C) / nrm;
}

// ---------------- R8 fallback: global native atomics ----------------
__global__ __launch_bounds__(256) void prep_acc_kernel(float2* __restrict__ acc, int N) {
    int i = blockIdx.x * blockDim.x + threadIdx.x;
    if (i < N) acc[i] = make_float2(0.0f, 0.0f);
}

__global__ __launch_bounds__(256) void edge_scatter_sincos_kernel(
        const int* __restrict__ esrc,
        const int* __restrict__ edst,
        const float* __restrict__ x,
        float2* __restrict__ acc, int E) {
    const int i = (blockIdx.x * 256 + threadIdx.x) * 4;
    float* accf = (float*)acc;
    for (int k = i; k < min(i + 4, E); ++k) {
        float sn, cs;
        __sincosf(x[esrc[k]], &sn, &cs);
        const int d = edst[k];
        unsafeAtomicAdd(&accf[2 * d],     cs);
        unsafeAtomicAdd(&accf[2 * d + 1], sn);
    }
}

__global__ __launch_bounds__(256) void node_kernel(
        const float* __restrict__ theta,
        const float2* __restrict__ acc,
        float* __restrict__ out, int N) {
    int n = blockIdx.x * blockDim.x + threadIdx.x;
    if (n >= N) return;
    float sn, cs;
    __sincosf(theta[n], &sn, &cs);
    const float2 a = acc[n];
    const float nrm = fmaxf(sqrtf(a.x * a.x + a.y * a.y), EPS);
    out[3 * n + 0] = cs;
    out[3 * n + 1] = sn;
    out[3 * n + 2] = (cs * a.y - sn * a.x) / nrm;
}

extern "C" void kernel_launch(void* const* d_in, const int* in_sizes, int n_in,
                              void* d_out, int out_size, void* d_ws, size_t ws_size,
                              hipStream_t stream) {
    const float* x     = (const float*)d_in[0];
    const float* theta = (const float*)d_in[1];
    const int*   esrc  = (const int*)d_in[2];
    const int*   edst  = (const int*)d_in[3];
    float*       out   = (float*)d_out;

    const int N = in_sizes[0];
    const int E = in_sizes[2];

    // ---------- R22 main path: sharded bin -> partials accum ------------
    if (N <= NPART * RNODES && N < (1 << 19)
        && (size_t)(N + 1) <= (size_t)NBIN * BINBLK) {
        const int nslice = 32;                       // accum grid 512 = 2/CU
        const size_t part_bytes = (size_t)NPART * nslice * RNODES * 8ull;
        const size_t pu_bytes   = (((size_t)(N + 1) * 8ull) + 15) & ~(size_t)15;
        const size_t rec_bytes  = (size_t)NBIN * NPART * CAP * 4ull;
        const size_t cnt_bytes  = (size_t)NBIN * NPART * 4ull;
        const size_t ofc_bytes  = 64;
        const size_t ofl_bytes  = (size_t)OCAP * 8ull;
        const size_t total = part_bytes + pu_bytes + rec_bytes + cnt_bytes
                           + ofc_bytes + ofl_bytes;
        if (ws_size >= total) {
            char* w = (char*)d_ws;
            unsigned long long* partials = (unsigned long long*)w; w += part_bytes;
            unsigned long long* pu       = (unsigned long long*)w; w += pu_bytes;
            unsigned*           records  = (unsigned*)w;           w += rec_bytes;
            int*                counts   = (int*)w;                w += cnt_bytes;
            int*                oflow_cnt= (int*)w;                w += ofc_bytes;
            unsigned long long* oflow    = (unsigned long long*)w;

            hipMemsetAsync(oflow_cnt, 0, sizeof(int), stream);
            bin_kernel<<<NBIN, BINBLK, 0, stream>>>(
                x, esrc, edst, pu, records, counts, oflow, oflow_cnt, E, N);
            accum_kernel<<<NPART * nslice, BLK, 0, stream>>>(
                pu, records, counts, oflow, oflow_cnt, partials, nslice);
            reduce_kernel<<<(N + 255) / 256, 256, 0, stream>>>(
                theta, partials, out, N, RNODES, nslice);
            return;
        }
    }

    // ---------- R15 fallback: NPART=16 rescan, 32 waves/CU ----------
    {
        const int R = (N + NPART - 1) / NPART;
        const size_t pu_bytes = (size_t)N * sizeof(unsigned long long);
        if (R <= RMAX) {
            for (int nslice : {32, 16, 8}) {
                const size_t part_bytes =
                    (size_t)NPART * nslice * R * sizeof(unsigned long long);
                if (ws_size >= part_bytes + pu_bytes) {
                    unsigned long long* partials = (unsigned long long*)d_ws;
                    unsigned long long* pu =
                        (unsigned long long*)((char*)d_ws + part_bytes);
                    prep_pack_kernel<<<(N + 255) / 256, 256, 0, stream>>>(
                        x, pu, N);
                    scatter_kernel<<<NPART * nslice, BLK, 0, stream>>>(
                        pu, esrc, edst, partials, E, R, nslice);
                    reduce_kernel<<<(N + 255) / 256, 256, 0, stream>>>(
                        theta, partials, out, N, R, nslice);
                    return;
                }
            }
        }
    }

    // ---------- R8 fallback: global native atomics ----------
    float2* acc = (float2*)d_ws;   // 800KB
    prep_acc_kernel<<<(N + 255) / 256, 256, 0, stream>>>(acc, N);
    edge_scatter_sincos_kernel<<<(E + 1023) / 1024, 256, 0, stream>>>(esrc, edst, x, acc, E);
    node_kernel<<<(N + 255) / 256, 256, 0, stream>>>(theta, acc, out, N);
}